// Round 1
// baseline (674.947 us; speedup 1.0000x reference)
//
#include <hip/hip_runtime.h>

typedef unsigned short u16;
typedef __bf16 bf16x8 __attribute__((ext_vector_type(8)));
typedef float f32x4 __attribute__((ext_vector_type(4)));
typedef unsigned short us8 __attribute__((ext_vector_type(8)));
typedef unsigned short us4 __attribute__((ext_vector_type(4)));

#define B_ 4
#define S_ 2048
#define D_ 1024
#define H_ 16
#define HD_ 64
#define EPS_ 1e-5f

__device__ __forceinline__ u16 f2bf(float f) {
  unsigned u = __builtin_bit_cast(unsigned, f);
  u = (u + 0x7FFFu + ((u >> 16) & 1u)) >> 16;
  return (u16)u;
}

__device__ __forceinline__ float gelu_f(float x) {
  return 0.5f * x * (1.0f + erff(x * 0.70710678118654752f));
}

// ---------------- weight transpose + f32->bf16 convert: W[K][N] -> Wt[N][K] ----------------
__global__ __launch_bounds__(256) void wconv_kernel(const float* __restrict__ W,
                                                    u16* __restrict__ Wt,
                                                    int Kd, int N) {
  __shared__ u16 tile[32][33];
  int bid = blockIdx.x;
  int nbn = N >> 5;
  int tk = bid / nbn, tn = bid % nbn;
  int tx = threadIdx.x & 31, ty = threadIdx.x >> 5;  // ty: 0..7
#pragma unroll
  for (int i = 0; i < 4; i++) {
    int r = ty + i * 8;
    tile[r][tx] = f2bf(W[(size_t)(tk * 32 + r) * N + tn * 32 + tx]);
  }
  __syncthreads();
#pragma unroll
  for (int i = 0; i < 4; i++) {
    int r = ty + i * 8;
    Wt[(size_t)(tn * 32 + r) * Kd + tk * 32 + tx] = tile[tx][r];
  }
}

// ---------------- LayerNorm: f32 in -> bf16 out, one block per row (D=1024) ----------------
__global__ __launch_bounds__(256) void ln_kernel(const float* __restrict__ x,
                                                 const float* __restrict__ w,
                                                 const float* __restrict__ b,
                                                 u16* __restrict__ out) {
  int row = blockIdx.x;
  int t = threadIdx.x;
  int lane = t & 63, wid = t >> 6;
  const float4* xr = (const float4*)(x + (size_t)row * D_);
  float4 v = xr[t];
  float s = v.x + v.y + v.z + v.w;
  float q = v.x * v.x + v.y * v.y + v.z * v.z + v.w * v.w;
#pragma unroll
  for (int off = 1; off < 64; off <<= 1) {
    s += __shfl_xor(s, off);
    q += __shfl_xor(q, off);
  }
  __shared__ float red[8];
  if (lane == 0) { red[wid] = s; red[4 + wid] = q; }
  __syncthreads();
  s = red[0] + red[1] + red[2] + red[3];
  q = red[4] + red[5] + red[6] + red[7];
  float mu = s * (1.0f / D_);
  float var = q * (1.0f / D_) - mu * mu;
  float rs = rsqrtf(var + EPS_);
  int c = t * 4;
  float4 wv = *(const float4*)(w + c);
  float4 bv = *(const float4*)(b + c);
  us4 o;
  o[0] = f2bf((v.x - mu) * rs * wv.x + bv.x);
  o[1] = f2bf((v.y - mu) * rs * wv.y + bv.y);
  o[2] = f2bf((v.z - mu) * rs * wv.z + bv.z);
  o[3] = f2bf((v.w - mu) * rs * wv.w + bv.w);
  *(us4*)(out + (size_t)row * D_ + c) = o;
}

// ---------------- GEMM: C[M,N] = A[M,K](bf16) * W[K,N], W given as Wt[N][K] bf16 -----------
// MODE bits: 1=bias, 2=gelu, 4=residual(f32), 8=bf16 out, 16=QKV interleaved split store
template <int MODE>
__global__ __launch_bounds__(256) void gemm_kernel(
    const u16* __restrict__ A, const u16* __restrict__ Bt,
    const float* __restrict__ bias, const float* __restrict__ res,
    float* __restrict__ Cf, u16* __restrict__ Cb,
    u16* __restrict__ Qc, u16* __restrict__ Kc, u16* __restrict__ Vt,
    int M, int N, int K) {
  __shared__ __align__(16) u16 Al[128 * 32];
  __shared__ __align__(16) u16 Bl[128 * 32];
  int t = threadIdx.x;
  int nbn = N >> 7;
  int bm = blockIdx.x / nbn, bn = blockIdx.x % nbn;
  int lane = t & 63, wid = t >> 6;
  int wm = wid >> 1, wn = wid & 1;
  int lrow = lane & 15, lgr = lane >> 4;
  const u16* Ab = A + (size_t)bm * 128 * K;
  const u16* Bb = Bt + (size_t)bn * 128 * K;
  int r1 = t >> 2, c1 = (t & 3) << 3;
  int r2 = r1 + 64;
  f32x4 acc[4][4] = {};
  for (int k0 = 0; k0 < K; k0 += 32) {
    us8 a1 = *(const us8*)(Ab + (size_t)r1 * K + k0 + c1);
    us8 a2 = *(const us8*)(Ab + (size_t)r2 * K + k0 + c1);
    us8 b1 = *(const us8*)(Bb + (size_t)r1 * K + k0 + c1);
    us8 b2 = *(const us8*)(Bb + (size_t)r2 * K + k0 + c1);
    __syncthreads();
    *(us8*)&Al[r1 * 32 + c1] = a1;
    *(us8*)&Al[r2 * 32 + c1] = a2;
    *(us8*)&Bl[r1 * 32 + c1] = b1;
    *(us8*)&Bl[r2 * 32 + c1] = b2;
    __syncthreads();
    bf16x8 af[4], bfr[4];
#pragma unroll
    for (int m = 0; m < 4; m++)
      af[m] = *(const bf16x8*)&Al[(wm * 64 + m * 16 + lrow) * 32 + lgr * 8];
#pragma unroll
    for (int n = 0; n < 4; n++)
      bfr[n] = *(const bf16x8*)&Bl[(wn * 64 + n * 16 + lrow) * 32 + lgr * 8];
#pragma unroll
    for (int m = 0; m < 4; m++)
#pragma unroll
      for (int n = 0; n < 4; n++)
        acc[m][n] = __builtin_amdgcn_mfma_f32_16x16x32_bf16(af[m], bfr[n], acc[m][n], 0, 0, 0);
  }
  // epilogue
#pragma unroll
  for (int m = 0; m < 4; m++) {
#pragma unroll
    for (int n = 0; n < 4; n++) {
#pragma unroll
      for (int r = 0; r < 4; r++) {
        int row = bm * 128 + wm * 64 + m * 16 + lgr * 4 + r;
        int col = bn * 128 + wn * 64 + n * 16 + lrow;
        float v = acc[m][n][r];
        if (MODE & 1) v += bias[col];
        if (MODE & 2) v = gelu_f(v);
        if (MODE & 4) v += res[(size_t)row * N + col];
        if (MODE & 16) {
          // col factors as (h, hd, c) with c fastest; c=0:K, c=1:Q, c=2:V
          int c = col % 3;
          int hd = (col / 3) & 63;
          int h = col / 192;
          int bb = row >> 11, sIdx = row & 2047;
          u16 bv = f2bf(v);
          size_t bh = (size_t)(bb * H_ + h);
          if (c == 0)      Kc[(bh * S_ + sIdx) * HD_ + hd] = bv;
          else if (c == 1) Qc[(bh * S_ + sIdx) * HD_ + hd] = bv;
          else             Vt[(bh * HD_ + hd) * S_ + sIdx] = bv;
        } else if (MODE & 8) {
          Cb[(size_t)row * N + col] = f2bf(v);
        } else {
          Cf[(size_t)row * N + col] = v;
        }
      }
    }
  }
}

// ---------------- causal flash attention: Q,K [bh][S][64] bf16, Vt [bh][64][S] bf16 --------
__global__ __launch_bounds__(256) void attn_kernel(const u16* __restrict__ Q,
                                                   const u16* __restrict__ Kk,
                                                   const u16* __restrict__ Vt,
                                                   u16* __restrict__ ctx) {
  __shared__ __align__(16) u16 Pl[4][2][512];  // per-wave private: [wave][qi2][16 rows][32 keys]
  int t = threadIdx.x, lane = t & 63, wid = t >> 6;
  int nqt = S_ / 128;
  int bh = blockIdx.x / nqt, qt = blockIdx.x % nqt;
  int b = bh >> 4, h = bh & 15;
  const u16* Qh = Q + (size_t)bh * S_ * HD_;
  const u16* Kh = Kk + (size_t)bh * S_ * HD_;
  const u16* Vh = Vt + (size_t)bh * HD_ * S_;
  int qbase = qt * 128 + wid * 32;
  int lrow = lane & 15, lgr = lane >> 4;

  bf16x8 qf[2][2];
#pragma unroll
  for (int qi = 0; qi < 2; qi++)
#pragma unroll
    for (int kb = 0; kb < 2; kb++)
      qf[qi][kb] = *(const bf16x8*)(Qh + (size_t)(qbase + qi * 16 + lrow) * HD_ + kb * 32 + lgr * 8);

  f32x4 o[2][4] = {};
  float mrun[2][4], lrun[2][4];
#pragma unroll
  for (int qi = 0; qi < 2; qi++)
#pragma unroll
    for (int r = 0; r < 4; r++) { mrun[qi][r] = -1e30f; lrun[qi][r] = 0.f; }

  int ktmax = qbase >> 5;  // inclusive
  for (int kt = 0; kt <= ktmax; kt++) {
    int kb32 = kt * 32;
    bf16x8 kf[2][2];
#pragma unroll
    for (int ki = 0; ki < 2; ki++)
#pragma unroll
      for (int kb = 0; kb < 2; kb++)
        kf[ki][kb] = *(const bf16x8*)(Kh + (size_t)(kb32 + ki * 16 + lrow) * HD_ + kb * 32 + lgr * 8);

    f32x4 s[2][2];
#pragma unroll
    for (int qi = 0; qi < 2; qi++)
#pragma unroll
      for (int ki = 0; ki < 2; ki++) {
        f32x4 z = {0.f, 0.f, 0.f, 0.f};
        z = __builtin_amdgcn_mfma_f32_16x16x32_bf16(qf[qi][0], kf[ki][0], z, 0, 0, 0);
        z = __builtin_amdgcn_mfma_f32_16x16x32_bf16(qf[qi][1], kf[ki][1], z, 0, 0, 0);
        s[qi][ki] = z;
      }

#pragma unroll
    for (int qi = 0; qi < 2; qi++) {
      float rmax[4];
#pragma unroll
      for (int r = 0; r < 4; r++) {
        int qrow = qbase + qi * 16 + lgr * 4 + r;
#pragma unroll
        for (int ki = 0; ki < 2; ki++) {
          float v = s[qi][ki][r] * 0.125f;
          int kcol = kb32 + ki * 16 + lrow;
          if (kcol > qrow) v = -1e30f;
          s[qi][ki][r] = v;
        }
        rmax[r] = fmaxf(s[qi][0][r], s[qi][1][r]);
      }
#pragma unroll
      for (int r = 0; r < 4; r++)
#pragma unroll
        for (int off = 1; off < 16; off <<= 1)
          rmax[r] = fmaxf(rmax[r], __shfl_xor(rmax[r], off));
      float corr[4];
#pragma unroll
      for (int r = 0; r < 4; r++) {
        float mnew = fmaxf(mrun[qi][r], rmax[r]);
        float c = __expf(mrun[qi][r] - mnew);
        corr[r] = c;
        mrun[qi][r] = mnew;
        float p0 = __expf(s[qi][0][r] - mnew);
        float p1 = __expf(s[qi][1][r] - mnew);
        s[qi][0][r] = p0;
        s[qi][1][r] = p1;
        float rsum = p0 + p1;
#pragma unroll
        for (int off = 1; off < 16; off <<= 1) rsum += __shfl_xor(rsum, off);
        lrun[qi][r] = lrun[qi][r] * c + rsum;
      }
#pragma unroll
      for (int nb = 0; nb < 4; nb++)
#pragma unroll
        for (int r = 0; r < 4; r++) o[qi][nb][r] *= corr[r];
#pragma unroll
      for (int ki = 0; ki < 2; ki++)
#pragma unroll
        for (int r = 0; r < 4; r++)
          Pl[wid][qi][(lgr * 4 + r) * 32 + ki * 16 + lrow] = f2bf(s[qi][ki][r]);
    }

    bf16x8 pf[2];
    pf[0] = *(const bf16x8*)&Pl[wid][0][lrow * 32 + lgr * 8];
    pf[1] = *(const bf16x8*)&Pl[wid][1][lrow * 32 + lgr * 8];
#pragma unroll
    for (int nb = 0; nb < 4; nb++) {
      bf16x8 vf = *(const bf16x8*)(Vh + (size_t)(nb * 16 + lrow) * S_ + kb32 + lgr * 8);
      o[0][nb] = __builtin_amdgcn_mfma_f32_16x16x32_bf16(pf[0], vf, o[0][nb], 0, 0, 0);
      o[1][nb] = __builtin_amdgcn_mfma_f32_16x16x32_bf16(pf[1], vf, o[1][nb], 0, 0, 0);
    }
  }

#pragma unroll
  for (int qi = 0; qi < 2; qi++) {
#pragma unroll
    for (int r = 0; r < 4; r++) {
      float inv = 1.0f / lrun[qi][r];
      int srow = qbase + qi * 16 + lgr * 4 + r;
      size_t base = ((size_t)b * S_ + srow) * D_ + h * HD_;
#pragma unroll
      for (int nb = 0; nb < 4; nb++)
        ctx[base + nb * 16 + lrow] = f2bf(o[qi][nb][r] * inv);
    }
  }
}

extern "C" void kernel_launch(void* const* d_in, const int* in_sizes, int n_in,
                              void* d_out, int out_size, void* d_ws, size_t ws_size,
                              hipStream_t stream) {
  const float* x = (const float*)d_in[0];
  const float* ln1w = (const float*)d_in[1];
  const float* ln1b = (const float*)d_in[2];
  const float* wqkv = (const float*)d_in[3];
  const float* wproj = (const float*)d_in[4];
  const float* bproj = (const float*)d_in[5];
  const float* ln2w = (const float*)d_in[6];
  const float* ln2b = (const float*)d_in[7];
  const float* wff1 = (const float*)d_in[8];
  const float* bff1 = (const float*)d_in[9];
  const float* wff2 = (const float*)d_in[10];
  const float* bff2 = (const float*)d_in[11];

  char* ws = (char*)d_ws;
  u16* wqkvT = (u16*)(ws + 0);                 //  6 MB  [3072][1024]
  u16* wprojT = (u16*)(ws + 6291456);          //  2 MB  [1024][1024]
  u16* wff1T = (u16*)(ws + 8388608);           //  8 MB  [4096][1024]
  u16* wff2T = (u16*)(ws + 16777216);          //  8 MB  [1024][4096]
  u16* h1 = (u16*)(ws + 25165824);             // 16 MB  [8192][1024]
  u16* Qc = (u16*)(ws + 41943040);             // 16 MB  [B*H][S][64]
  u16* Kc = (u16*)(ws + 58720256);             // 16 MB
  u16* Vt = (u16*)(ws + 75497472);             // 16 MB  [B*H][64][S]
  u16* ctx = (u16*)(ws + 92274688);            // 16 MB  [8192][1024]
  float* x1 = (float*)(ws + 109051904);        // 32 MB  [8192][1024]
  u16* h2 = (u16*)(ws + 142606336);            // 16 MB
  u16* g = (u16*)(ws + 25165824);              // 64 MB  [8192][4096], reuses h1..Vt
  float* outp = (float*)d_out;

  // weight convert+transpose
  wconv_kernel<<<(1024 / 32) * (3072 / 32), 256, 0, stream>>>(wqkv, wqkvT, 1024, 3072);
  wconv_kernel<<<(1024 / 32) * (1024 / 32), 256, 0, stream>>>(wproj, wprojT, 1024, 1024);
  wconv_kernel<<<(1024 / 32) * (4096 / 32), 256, 0, stream>>>(wff1, wff1T, 1024, 4096);
  wconv_kernel<<<(4096 / 32) * (1024 / 32), 256, 0, stream>>>(wff2, wff2T, 4096, 1024);

  // LN1
  ln_kernel<<<8192, 256, 0, stream>>>(x, ln1w, ln1b, h1);
  // QKV projection with interleaved split (c=0:K, 1:Q, 2:V), V stored transposed
  gemm_kernel<16><<<64 * 24, 256, 0, stream>>>(h1, wqkvT, nullptr, nullptr, nullptr, nullptr,
                                               Qc, Kc, Vt, 8192, 3072, 1024);
  // attention
  attn_kernel<<<4 * 16 * (S_ / 128), 256, 0, stream>>>(Qc, Kc, Vt, ctx);
  // proj + bias + residual(x) -> x1 (f32)
  gemm_kernel<5><<<64 * 8, 256, 0, stream>>>(ctx, wprojT, bproj, x, x1, nullptr,
                                             nullptr, nullptr, nullptr, 8192, 1024, 1024);
  // LN2
  ln_kernel<<<8192, 256, 0, stream>>>(x1, ln2w, ln2b, h2);
  // FF1 + bias + exact GELU -> g (bf16)
  gemm_kernel<11><<<64 * 32, 256, 0, stream>>>(h2, wff1T, bff1, nullptr, nullptr, g,
                                               nullptr, nullptr, nullptr, 8192, 4096, 1024);
  // FF2 + bias + residual(x1) -> out (f32)
  gemm_kernel<5><<<64 * 8, 256, 0, stream>>>(g, wff2T, bff2, x1, outp, nullptr,
                                             nullptr, nullptr, nullptr, 8192, 1024, 4096);
}

// Round 2
// 532.498 us; speedup vs baseline: 1.2675x; 1.2675x over previous
//
#include <hip/hip_runtime.h>

typedef unsigned short u16;
typedef __bf16 bf16x8 __attribute__((ext_vector_type(8)));
typedef float f32x4 __attribute__((ext_vector_type(4)));
typedef unsigned short us8 __attribute__((ext_vector_type(8)));
typedef unsigned short us4 __attribute__((ext_vector_type(4)));

#define B_ 4
#define S_ 2048
#define D_ 1024
#define H_ 16
#define HD_ 64
#define EPS_ 1e-5f
#define PSTR 40  // P LDS row stride (elems): 80B rows -> b128 reads spread over all 8 bank groups

__device__ __forceinline__ u16 f2bf(float f) {
  unsigned u = __builtin_bit_cast(unsigned, f);
  u = (u + 0x7FFFu + ((u >> 16) & 1u)) >> 16;
  return (u16)u;
}

__device__ __forceinline__ float gelu_f(float x) {
  return 0.5f * x * (1.0f + erff(x * 0.70710678118654752f));
}

typedef const __attribute__((address_space(1))) unsigned int* gp1;
typedef __attribute__((address_space(3))) unsigned int* lp3;
__device__ __forceinline__ void gl_lds16(const void* g, void* l) {
  __builtin_amdgcn_global_load_lds((gp1)(unsigned long long)g,
                                   (lp3)(unsigned int)(unsigned long long)l,
                                   16, 0, 0);
}

// ---------------- weight transpose + f32->bf16 convert: W[K][N] -> Wt[N][K] ----------------
__global__ __launch_bounds__(256) void wconv_kernel(const float* __restrict__ W,
                                                    u16* __restrict__ Wt,
                                                    int Kd, int N) {
  __shared__ u16 tile[32][33];
  int bid = blockIdx.x;
  int nbn = N >> 5;
  int tk = bid / nbn, tn = bid % nbn;
  int tx = threadIdx.x & 31, ty = threadIdx.x >> 5;
#pragma unroll
  for (int i = 0; i < 4; i++) {
    int r = ty + i * 8;
    tile[r][tx] = f2bf(W[(size_t)(tk * 32 + r) * N + tn * 32 + tx]);
  }
  __syncthreads();
#pragma unroll
  for (int i = 0; i < 4; i++) {
    int r = ty + i * 8;
    Wt[(size_t)(tn * 32 + r) * Kd + tk * 32 + tx] = tile[tx][r];
  }
}

// ---------------- LayerNorm: f32 in -> bf16 out, one block per row (D=1024) ----------------
__global__ __launch_bounds__(256) void ln_kernel(const float* __restrict__ x,
                                                 const float* __restrict__ w,
                                                 const float* __restrict__ b,
                                                 u16* __restrict__ out) {
  int row = blockIdx.x;
  int t = threadIdx.x;
  int lane = t & 63, wid = t >> 6;
  const float4* xr = (const float4*)(x + (size_t)row * D_);
  float4 v = xr[t];
  float s = v.x + v.y + v.z + v.w;
  float q = v.x * v.x + v.y * v.y + v.z * v.z + v.w * v.w;
#pragma unroll
  for (int off = 1; off < 64; off <<= 1) {
    s += __shfl_xor(s, off);
    q += __shfl_xor(q, off);
  }
  __shared__ float red[8];
  if (lane == 0) { red[wid] = s; red[4 + wid] = q; }
  __syncthreads();
  s = red[0] + red[1] + red[2] + red[3];
  q = red[4] + red[5] + red[6] + red[7];
  float mu = s * (1.0f / D_);
  float var = q * (1.0f / D_) - mu * mu;
  float rs = rsqrtf(var + EPS_);
  int c = t * 4;
  float4 wv = *(const float4*)(w + c);
  float4 bv = *(const float4*)(b + c);
  us4 o;
  o[0] = f2bf((v.x - mu) * rs * wv.x + bv.x);
  o[1] = f2bf((v.y - mu) * rs * wv.y + bv.y);
  o[2] = f2bf((v.z - mu) * rs * wv.z + bv.z);
  o[3] = f2bf((v.w - mu) * rs * wv.w + bv.w);
  *(us4*)(out + (size_t)row * D_ + c) = o;
}

// ---------------- GEMM (m97 structure): C = A[M,K] * Bt[N,K]^T, global_load_lds staging ----
// MODE bits: 1=bias, 2=gelu, 4=residual(f32), 8=bf16 out, 16=QKV interleaved split store
template <int MODE>
__global__ __launch_bounds__(256) void gemm_kernel(
    const u16* __restrict__ A, const u16* __restrict__ Bt,
    const float* __restrict__ bias, const float* __restrict__ res,
    float* __restrict__ Cf, u16* __restrict__ Cb,
    u16* __restrict__ Qc, u16* __restrict__ Kc, u16* __restrict__ Vt,
    int M, int N, int K) {
  __shared__ __align__(16) u16 Al[128 * 32];
  __shared__ __align__(16) u16 Bl[128 * 32];
  int t = threadIdx.x;
  int nbn = N >> 7;
  // bijective XCD swizzle (grids here are all divisible by 8)
  int nwg = gridDim.x;
  int cpx = nwg >> 3;
  int bid = (blockIdx.x % 8) * cpx + blockIdx.x / 8;
  int bm = bid / nbn, bn = bid % nbn;
  int lane = t & 63, wid = t >> 6;
  int wm = wid >> 1, wn = wid & 1;
  int lrow = lane & 15, lgr = lane >> 4;
  const u16* Ab = A + (size_t)bm * 128 * K;
  const u16* Bb = Bt + (size_t)bn * 128 * K;
  // staging geometry: wave w, instr j in {0,1}: LDS elems [(w*2+j)*512, +512), lane l -> +l*8
  int srow = wid * 32 + (lane >> 2);
  int scol = (lane & 3) * 8;
  u16* AlD0 = &Al[wid * 1024 + lane * 8];
  u16* BlD0 = &Bl[wid * 1024 + lane * 8];
  const u16* Ag0 = Ab + (size_t)srow * K + scol;
  const u16* Ag1 = Ab + (size_t)(srow + 16) * K + scol;
  const u16* Bg0 = Bb + (size_t)srow * K + scol;
  const u16* Bg1 = Bb + (size_t)(srow + 16) * K + scol;
  f32x4 acc[4][4] = {};
  for (int k0 = 0; k0 < K; k0 += 32) {
    gl_lds16(Ag0 + k0, AlD0);
    gl_lds16(Ag1 + k0, AlD0 + 512);
    gl_lds16(Bg0 + k0, BlD0);
    gl_lds16(Bg1 + k0, BlD0 + 512);
    __syncthreads();  // drains vmcnt(0): tile resident
    bf16x8 af[4], bfr[4];
#pragma unroll
    for (int m = 0; m < 4; m++)
      af[m] = *(const bf16x8*)&Al[(wm * 64 + m * 16 + lrow) * 32 + lgr * 8];
#pragma unroll
    for (int n = 0; n < 4; n++)
      bfr[n] = *(const bf16x8*)&Bl[(wn * 64 + n * 16 + lrow) * 32 + lgr * 8];
#pragma unroll
    for (int m = 0; m < 4; m++)
#pragma unroll
      for (int n = 0; n < 4; n++)
        acc[m][n] = __builtin_amdgcn_mfma_f32_16x16x32_bf16(af[m], bfr[n], acc[m][n], 0, 0, 0);
    __syncthreads();  // all waves done reading before next overwrite
  }
  // epilogue
#pragma unroll
  for (int m = 0; m < 4; m++) {
#pragma unroll
    for (int n = 0; n < 4; n++) {
#pragma unroll
      for (int r = 0; r < 4; r++) {
        int row = bm * 128 + wm * 64 + m * 16 + lgr * 4 + r;
        int col = bn * 128 + wn * 64 + n * 16 + lrow;
        float v = acc[m][n][r];
        if (MODE & 1) v += bias[col];
        if (MODE & 2) v = gelu_f(v);
        if (MODE & 4) v += res[(size_t)row * N + col];
        if (MODE & 16) {
          // col factors as (h, hd, c) with c fastest; c=0:K, c=1:Q (pre-scaled), c=2:V
          int c = col % 3;
          int hd = (col / 3) & 63;
          int h = col / 192;
          int bb = row >> 11, sIdx = row & 2047;
          size_t bh = (size_t)(bb * H_ + h);
          if (c == 0)      Kc[(bh * S_ + sIdx) * HD_ + hd] = f2bf(v);
          else if (c == 1) Qc[(bh * S_ + sIdx) * HD_ + hd] = f2bf(v * 0.125f);
          else             Vt[(bh * HD_ + hd) * S_ + sIdx] = f2bf(v);
        } else if (MODE & 8) {
          Cb[(size_t)row * N + col] = f2bf(v);
        } else {
          Cf[(size_t)row * N + col] = v;
        }
      }
    }
  }
}

// ---------------- causal flash attention -------------------------------------------------
// Q,K [bh][S][64] bf16 (Q pre-scaled by 0.125), Vt [bh][64][S] bf16.
// Per wave: 32 q rows. Interior: 64-key unmasked chunks; diagonal: 32-key masked chunk.
template <int NK, bool MASK>
__device__ __forceinline__ void attn_chunk(
    const u16* __restrict__ Kh, const u16* __restrict__ Vh, u16* PlW,
    const bf16x8 (&qf)[2][2], f32x4 (&o)[2][4],
    float (&mrun)[2][4], float (&lrun)[2][4],
    int kb, int qbase, int lrow, int lgr) {
  bf16x8 kf[NK][2];
#pragma unroll
  for (int ki = 0; ki < NK; ki++)
#pragma unroll
    for (int h = 0; h < 2; h++)
      kf[ki][h] = *(const bf16x8*)(Kh + (size_t)(kb + ki * 16 + lrow) * HD_ + h * 32 + lgr * 8);
  f32x4 s[2][NK];
#pragma unroll
  for (int qi = 0; qi < 2; qi++)
#pragma unroll
    for (int ki = 0; ki < NK; ki++) {
      f32x4 z = {0.f, 0.f, 0.f, 0.f};
      z = __builtin_amdgcn_mfma_f32_16x16x32_bf16(qf[qi][0], kf[ki][0], z, 0, 0, 0);
      z = __builtin_amdgcn_mfma_f32_16x16x32_bf16(qf[qi][1], kf[ki][1], z, 0, 0, 0);
      s[qi][ki] = z;
    }
#pragma unroll
  for (int qi = 0; qi < 2; qi++) {
    float corr[4];
#pragma unroll
    for (int r = 0; r < 4; r++) {
      if (MASK) {
        int qrow = qbase + qi * 16 + lgr * 4 + r;
#pragma unroll
        for (int ki = 0; ki < NK; ki++) {
          int kcol = kb + ki * 16 + lrow;
          if (kcol > qrow) s[qi][ki][r] = -1e30f;
        }
      }
      float rm = s[qi][0][r];
#pragma unroll
      for (int ki = 1; ki < NK; ki++) rm = fmaxf(rm, s[qi][ki][r]);
#pragma unroll
      for (int off = 1; off < 16; off <<= 1) rm = fmaxf(rm, __shfl_xor(rm, off));
      float mnew = fmaxf(mrun[qi][r], rm);
      float c = __expf(mrun[qi][r] - mnew);
      corr[r] = c;
      mrun[qi][r] = mnew;
      float rsum = 0.f;
#pragma unroll
      for (int ki = 0; ki < NK; ki++) {
        float p = __expf(s[qi][ki][r] - mnew);
        s[qi][ki][r] = p;
        rsum += p;
      }
#pragma unroll
      for (int off = 1; off < 16; off <<= 1) rsum += __shfl_xor(rsum, off);
      lrun[qi][r] = lrun[qi][r] * c + rsum;
#pragma unroll
      for (int ki = 0; ki < NK; ki++)
        PlW[qi * (16 * PSTR) + (lgr * 4 + r) * PSTR + ki * 16 + lrow] = f2bf(s[qi][ki][r]);
    }
#pragma unroll
    for (int nb = 0; nb < 4; nb++)
#pragma unroll
      for (int r = 0; r < 4; r++) o[qi][nb][r] *= corr[r];
  }
#pragma unroll
  for (int sub = 0; sub < NK / 2; sub++) {
    bf16x8 pf0 = *(const bf16x8*)&PlW[0 * (16 * PSTR) + lrow * PSTR + sub * 32 + lgr * 8];
    bf16x8 pf1 = *(const bf16x8*)&PlW[1 * (16 * PSTR) + lrow * PSTR + sub * 32 + lgr * 8];
#pragma unroll
    for (int nb = 0; nb < 4; nb++) {
      bf16x8 vf = *(const bf16x8*)(Vh + (size_t)(nb * 16 + lrow) * S_ + kb + sub * 32 + lgr * 8);
      o[0][nb] = __builtin_amdgcn_mfma_f32_16x16x32_bf16(pf0, vf, o[0][nb], 0, 0, 0);
      o[1][nb] = __builtin_amdgcn_mfma_f32_16x16x32_bf16(pf1, vf, o[1][nb], 0, 0, 0);
    }
  }
}

__global__ __launch_bounds__(256) void attn_kernel(const u16* __restrict__ Q,
                                                   const u16* __restrict__ Kk,
                                                   const u16* __restrict__ Vt,
                                                   u16* __restrict__ ctx) {
  __shared__ __align__(16) u16 Pl[4][2][16 * PSTR];
  int t = threadIdx.x, lane = t & 63, wid = t >> 6;
  int nbh = B_ * H_;
  // heavy q-tiles dispatched first (load balance under causal mask)
  int qt = (S_ / 128) - 1 - (int)(blockIdx.x / nbh);
  int bh = blockIdx.x % nbh;
  int b = bh >> 4, h = bh & 15;
  const u16* Qh = Q + (size_t)bh * S_ * HD_;
  const u16* Kh = Kk + (size_t)bh * S_ * HD_;
  const u16* Vh = Vt + (size_t)bh * HD_ * S_;
  u16* PlW = &Pl[wid][0][0];
  int qbase = qt * 128 + wid * 32;
  int lrow = lane & 15, lgr = lane >> 4;

  bf16x8 qf[2][2];
#pragma unroll
  for (int qi = 0; qi < 2; qi++)
#pragma unroll
    for (int kb = 0; kb < 2; kb++)
      qf[qi][kb] = *(const bf16x8*)(Qh + (size_t)(qbase + qi * 16 + lrow) * HD_ + kb * 32 + lgr * 8);

  f32x4 o[2][4] = {};
  float mrun[2][4], lrun[2][4];
#pragma unroll
  for (int qi = 0; qi < 2; qi++)
#pragma unroll
    for (int r = 0; r < 4; r++) { mrun[qi][r] = -1e30f; lrun[qi][r] = 0.f; }

  int nf64 = qbase >> 6;  // full 64-key chunks
  for (int kt = 0; kt < nf64; kt++)
    attn_chunk<4, false>(Kh, Vh, PlW, qf, o, mrun, lrun, kt * 64, qbase, lrow, lgr);
  if (qbase & 32)
    attn_chunk<2, false>(Kh, Vh, PlW, qf, o, mrun, lrun, qbase - 32, qbase, lrow, lgr);
  attn_chunk<2, true>(Kh, Vh, PlW, qf, o, mrun, lrun, qbase, qbase, lrow, lgr);

#pragma unroll
  for (int qi = 0; qi < 2; qi++) {
#pragma unroll
    for (int r = 0; r < 4; r++) {
      float inv = 1.0f / lrun[qi][r];
      int srow = qbase + qi * 16 + lgr * 4 + r;
      size_t base = ((size_t)b * S_ + srow) * D_ + h * HD_;
#pragma unroll
      for (int nb = 0; nb < 4; nb++)
        ctx[base + nb * 16 + lrow] = f2bf(o[qi][nb][r] * inv);
    }
  }
}

extern "C" void kernel_launch(void* const* d_in, const int* in_sizes, int n_in,
                              void* d_out, int out_size, void* d_ws, size_t ws_size,
                              hipStream_t stream) {
  const float* x = (const float*)d_in[0];
  const float* ln1w = (const float*)d_in[1];
  const float* ln1b = (const float*)d_in[2];
  const float* wqkv = (const float*)d_in[3];
  const float* wproj = (const float*)d_in[4];
  const float* bproj = (const float*)d_in[5];
  const float* ln2w = (const float*)d_in[6];
  const float* ln2b = (const float*)d_in[7];
  const float* wff1 = (const float*)d_in[8];
  const float* bff1 = (const float*)d_in[9];
  const float* wff2 = (const float*)d_in[10];
  const float* bff2 = (const float*)d_in[11];

  char* ws = (char*)d_ws;
  u16* wqkvT = (u16*)(ws + 0);                 //  6 MB  [3072][1024]
  u16* wprojT = (u16*)(ws + 6291456);          //  2 MB  [1024][1024]
  u16* wff1T = (u16*)(ws + 8388608);           //  8 MB  [4096][1024]
  u16* wff2T = (u16*)(ws + 16777216);          //  8 MB  [1024][4096]
  u16* h1 = (u16*)(ws + 25165824);             // 16 MB  [8192][1024]
  u16* Qc = (u16*)(ws + 41943040);             // 16 MB  [B*H][S][64]
  u16* Kc = (u16*)(ws + 58720256);             // 16 MB
  u16* Vt = (u16*)(ws + 75497472);             // 16 MB  [B*H][64][S]
  u16* ctx = (u16*)(ws + 92274688);            // 16 MB  [8192][1024]
  float* x1 = (float*)(ws + 109051904);        // 32 MB  [8192][1024]
  u16* h2 = (u16*)(ws + 142606336);            // 16 MB
  u16* g = (u16*)(ws + 25165824);              // 64 MB  [8192][4096], reuses h1..Vt
  float* outp = (float*)d_out;

  wconv_kernel<<<(1024 / 32) * (3072 / 32), 256, 0, stream>>>(wqkv, wqkvT, 1024, 3072);
  wconv_kernel<<<(1024 / 32) * (1024 / 32), 256, 0, stream>>>(wproj, wprojT, 1024, 1024);
  wconv_kernel<<<(1024 / 32) * (4096 / 32), 256, 0, stream>>>(wff1, wff1T, 1024, 4096);
  wconv_kernel<<<(4096 / 32) * (1024 / 32), 256, 0, stream>>>(wff2, wff2T, 4096, 1024);

  ln_kernel<<<8192, 256, 0, stream>>>(x, ln1w, ln1b, h1);
  gemm_kernel<16><<<64 * 24, 256, 0, stream>>>(h1, wqkvT, nullptr, nullptr, nullptr, nullptr,
                                               Qc, Kc, Vt, 8192, 3072, 1024);
  attn_kernel<<<4 * 16 * (S_ / 128), 256, 0, stream>>>(Qc, Kc, Vt, ctx);
  gemm_kernel<5><<<64 * 8, 256, 0, stream>>>(ctx, wprojT, bproj, x, x1, nullptr,
                                             nullptr, nullptr, nullptr, 8192, 1024, 1024);
  ln_kernel<<<8192, 256, 0, stream>>>(x1, ln2w, ln2b, h2);
  gemm_kernel<11><<<64 * 32, 256, 0, stream>>>(h2, wff1T, bff1, nullptr, nullptr, g,
                                               nullptr, nullptr, nullptr, 8192, 4096, 1024);
  gemm_kernel<5><<<64 * 8, 256, 0, stream>>>(g, wff2T, bff2, x1, outp, nullptr,
                                             nullptr, nullptr, nullptr, 8192, 1024, 4096);
}

// Round 3
// 527.297 us; speedup vs baseline: 1.2800x; 1.0099x over previous
//
#include <hip/hip_runtime.h>

typedef unsigned short u16;
typedef __bf16 bf16x8 __attribute__((ext_vector_type(8)));
typedef float f32x4 __attribute__((ext_vector_type(4)));
typedef unsigned short us8 __attribute__((ext_vector_type(8)));
typedef unsigned short us4 __attribute__((ext_vector_type(4)));

#define B_ 4
#define S_ 2048
#define D_ 1024
#define H_ 16
#define HD_ 64
#define EPS_ 1e-5f
#define PSTR 40  // P LDS row stride (elems)
#define SCALE_ (0.125f * 1.44269504088896341f)  // HD^-0.5 * log2(e); exp via exp2
#define THR_ 8.0f                               // defer-max threshold (log2 domain)

__device__ __forceinline__ u16 f2bf(float f) {
  unsigned u = __builtin_bit_cast(unsigned, f);
  u = (u + 0x7FFFu + ((u >> 16) & 1u)) >> 16;
  return (u16)u;
}

__device__ __forceinline__ float gelu_f(float x) {
  return 0.5f * x * (1.0f + erff(x * 0.70710678118654752f));
}

typedef const __attribute__((address_space(1))) unsigned int* gp1;
typedef __attribute__((address_space(3))) unsigned int* lp3;
__device__ __forceinline__ void gl_lds16(const void* g, void* l) {
  __builtin_amdgcn_global_load_lds((gp1)(unsigned long long)g,
                                   (lp3)(unsigned int)(unsigned long long)l,
                                   16, 0, 0);
}

// ---------------- weight transpose + f32->bf16 convert: W[K][N] -> Wt[N][K] ----------------
__global__ __launch_bounds__(256) void wconv_kernel(const float* __restrict__ W,
                                                    u16* __restrict__ Wt,
                                                    int Kd, int N) {
  __shared__ u16 tile[32][33];
  int bid = blockIdx.x;
  int nbn = N >> 5;
  int tk = bid / nbn, tn = bid % nbn;
  int tx = threadIdx.x & 31, ty = threadIdx.x >> 5;
#pragma unroll
  for (int i = 0; i < 4; i++) {
    int r = ty + i * 8;
    tile[r][tx] = f2bf(W[(size_t)(tk * 32 + r) * N + tn * 32 + tx]);
  }
  __syncthreads();
#pragma unroll
  for (int i = 0; i < 4; i++) {
    int r = ty + i * 8;
    Wt[(size_t)(tn * 32 + r) * Kd + tk * 32 + tx] = tile[tx][r];
  }
}

// ---------------- V transpose: Vc [bh][S][64] -> Vt [bh][64][S] ----------------------------
__global__ __launch_bounds__(256) void vtrans_kernel(const u16* __restrict__ Vc,
                                                     u16* __restrict__ Vt) {
  __shared__ u16 tile[64][72];
  int bh = blockIdx.x >> 5;
  int sb = blockIdx.x & 31;
  const u16* src = Vc + ((size_t)bh * S_ + sb * 64) * HD_;
  int r = threadIdx.x >> 2, c0 = (threadIdx.x & 3) * 16;
  *(us8*)&tile[r][c0] = *(const us8*)(src + r * HD_ + c0);
  *(us8*)&tile[r][c0 + 8] = *(const us8*)(src + r * HD_ + c0 + 8);
  __syncthreads();
  u16* dst = Vt + (size_t)bh * HD_ * S_ + sb * 64;
  int hd = threadIdx.x >> 2;
  int s0 = (threadIdx.x & 3) * 16;
  us8 a, b;
#pragma unroll
  for (int j = 0; j < 8; j++) a[j] = tile[s0 + j][hd];
#pragma unroll
  for (int j = 0; j < 8; j++) b[j] = tile[s0 + 8 + j][hd];
  *(us8*)(dst + (size_t)hd * S_ + s0) = a;
  *(us8*)(dst + (size_t)hd * S_ + s0 + 8) = b;
}

// ---------------- LayerNorm: f32 in -> bf16 out, one block per row (D=1024) ----------------
__global__ __launch_bounds__(256) void ln_kernel(const float* __restrict__ x,
                                                 const float* __restrict__ w,
                                                 const float* __restrict__ b,
                                                 u16* __restrict__ out) {
  int row = blockIdx.x;
  int t = threadIdx.x;
  int lane = t & 63, wid = t >> 6;
  const float4* xr = (const float4*)(x + (size_t)row * D_);
  float4 v = xr[t];
  float s = v.x + v.y + v.z + v.w;
  float q = v.x * v.x + v.y * v.y + v.z * v.z + v.w * v.w;
#pragma unroll
  for (int off = 1; off < 64; off <<= 1) {
    s += __shfl_xor(s, off);
    q += __shfl_xor(q, off);
  }
  __shared__ float red[8];
  if (lane == 0) { red[wid] = s; red[4 + wid] = q; }
  __syncthreads();
  s = red[0] + red[1] + red[2] + red[3];
  q = red[4] + red[5] + red[6] + red[7];
  float mu = s * (1.0f / D_);
  float var = q * (1.0f / D_) - mu * mu;
  float rs = rsqrtf(var + EPS_);
  int c = t * 4;
  float4 wv = *(const float4*)(w + c);
  float4 bv = *(const float4*)(b + c);
  us4 o;
  o[0] = f2bf((v.x - mu) * rs * wv.x + bv.x);
  o[1] = f2bf((v.y - mu) * rs * wv.y + bv.y);
  o[2] = f2bf((v.z - mu) * rs * wv.z + bv.z);
  o[3] = f2bf((v.w - mu) * rs * wv.w + bv.w);
  *(us4*)(out + (size_t)row * D_ + c) = o;
}

// ---------------- GEMM (m97 structure): C = A[M,K] * Bt[N,K]^T, global_load_lds staging ----
// MODE bits: 1=bias, 2=gelu, 4=residual(f32), 8=bf16 out, 16=QKV interleaved split store
template <int MODE>
__global__ __launch_bounds__(256) void gemm_kernel(
    const u16* __restrict__ A, const u16* __restrict__ Bt,
    const float* __restrict__ bias, const float* __restrict__ res,
    float* __restrict__ Cf, u16* __restrict__ Cb,
    u16* __restrict__ Qc, u16* __restrict__ Kc, u16* __restrict__ Vc,
    int M, int N, int K) {
  __shared__ __align__(16) u16 Al[128 * 32];
  __shared__ __align__(16) u16 Bl[128 * 32];
  int t = threadIdx.x;
  int nbn = N >> 7;
  int nwg = gridDim.x;
  int cpx = nwg >> 3;
  int bid = (blockIdx.x % 8) * cpx + blockIdx.x / 8;
  int bm = bid / nbn, bn = bid % nbn;
  int lane = t & 63, wid = t >> 6;
  int wm = wid >> 1, wn = wid & 1;
  int lrow = lane & 15, lgr = lane >> 4;
  const u16* Ab = A + (size_t)bm * 128 * K;
  const u16* Bb = Bt + (size_t)bn * 128 * K;
  int srow = wid * 32 + (lane >> 2);
  int scol = (lane & 3) * 8;
  u16* AlD0 = &Al[wid * 1024 + lane * 8];
  u16* BlD0 = &Bl[wid * 1024 + lane * 8];
  const u16* Ag0 = Ab + (size_t)srow * K + scol;
  const u16* Ag1 = Ab + (size_t)(srow + 16) * K + scol;
  const u16* Bg0 = Bb + (size_t)srow * K + scol;
  const u16* Bg1 = Bb + (size_t)(srow + 16) * K + scol;
  f32x4 acc[4][4] = {};
  for (int k0 = 0; k0 < K; k0 += 32) {
    gl_lds16(Ag0 + k0, AlD0);
    gl_lds16(Ag1 + k0, AlD0 + 512);
    gl_lds16(Bg0 + k0, BlD0);
    gl_lds16(Bg1 + k0, BlD0 + 512);
    __syncthreads();
    bf16x8 af[4], bfr[4];
#pragma unroll
    for (int m = 0; m < 4; m++)
      af[m] = *(const bf16x8*)&Al[(wm * 64 + m * 16 + lrow) * 32 + lgr * 8];
#pragma unroll
    for (int n = 0; n < 4; n++)
      bfr[n] = *(const bf16x8*)&Bl[(wn * 64 + n * 16 + lrow) * 32 + lgr * 8];
#pragma unroll
    for (int m = 0; m < 4; m++)
#pragma unroll
      for (int n = 0; n < 4; n++)
        acc[m][n] = __builtin_amdgcn_mfma_f32_16x16x32_bf16(af[m], bfr[n], acc[m][n], 0, 0, 0);
    __syncthreads();
  }
  // epilogue: n outer so col-derived address math is hoisted (4x instead of 64x)
#pragma unroll
  for (int n = 0; n < 4; n++) {
    int col = bn * 128 + wn * 64 + n * 16 + lrow;
    float bv = (MODE & 1) ? bias[col] : 0.0f;
    if (MODE & 16) {
      // col factors as (h, hd, c) with c fastest; c=0:K, c=1:Q, c=2:V (all [bh][S][64])
      int c = col % 3;
      int hd = (col / 3) & 63;
      int h = col / 192;
      u16* dst = (c == 0) ? Kc : (c == 1) ? Qc : Vc;
#pragma unroll
      for (int m = 0; m < 4; m++)
#pragma unroll
        for (int r = 0; r < 4; r++) {
          int row = bm * 128 + wm * 64 + m * 16 + lgr * 4 + r;
          int bb = row >> 11, sIdx = row & 2047;
          dst[(((size_t)(bb * H_ + h)) * S_ + sIdx) * HD_ + hd] = f2bf(acc[m][n][r]);
        }
    } else {
#pragma unroll
      for (int m = 0; m < 4; m++)
#pragma unroll
        for (int r = 0; r < 4; r++) {
          int row = bm * 128 + wm * 64 + m * 16 + lgr * 4 + r;
          float v = acc[m][n][r] + bv;
          if (MODE & 2) v = gelu_f(v);
          if (MODE & 4) v += res[(size_t)row * N + col];
          if (MODE & 8) Cb[(size_t)row * N + col] = f2bf(v);
          else          Cf[(size_t)row * N + col] = v;
        }
    }
  }
}

// ---------------- causal flash attention -------------------------------------------------
// Q,K [bh][S][64] bf16, Vt [bh][64][S] bf16. One wave per 32 q rows.
// Defer-max (THR=8, log2 domain) + per-lane deferred l-sum (reduced once at end).
template <int NK, bool MASK>
__device__ __forceinline__ void attn_chunk(
    const u16* __restrict__ Kh, const u16* __restrict__ Vh, u16* PlW,
    const bf16x8 (&qf)[2][2], f32x4 (&o)[2][4],
    float (&mrun)[2][4], float (&lrun)[2][4],
    int kb, int qbase, int lrow, int lgr) {
  bf16x8 kf[NK][2];
#pragma unroll
  for (int ki = 0; ki < NK; ki++)
#pragma unroll
    for (int h = 0; h < 2; h++)
      kf[ki][h] = *(const bf16x8*)(Kh + (size_t)(kb + ki * 16 + lrow) * HD_ + h * 32 + lgr * 8);
  f32x4 s[2][NK];
#pragma unroll
  for (int qi = 0; qi < 2; qi++)
#pragma unroll
    for (int ki = 0; ki < NK; ki++) {
      f32x4 z = {0.f, 0.f, 0.f, 0.f};
      z = __builtin_amdgcn_mfma_f32_16x16x32_bf16(qf[qi][0], kf[ki][0], z, 0, 0, 0);
      z = __builtin_amdgcn_mfma_f32_16x16x32_bf16(qf[qi][1], kf[ki][1], z, 0, 0, 0);
      s[qi][ki] = z;
    }
  float rm[2][4];
  bool ok = true;
#pragma unroll
  for (int qi = 0; qi < 2; qi++)
#pragma unroll
    for (int r = 0; r < 4; r++) {
      float m0 = -3.0e38f;
#pragma unroll
      for (int ki = 0; ki < NK; ki++) {
        float v = s[qi][ki][r] * SCALE_;
        if (MASK) {
          int qrow = qbase + qi * 16 + lgr * 4 + r;
          int kcol = kb + ki * 16 + lrow;
          if (kcol > qrow) v = -3.0e38f;
        }
        s[qi][ki][r] = v;
        m0 = fmaxf(m0, v);
      }
      rm[qi][r] = m0;
      ok = ok && (m0 <= mrun[qi][r] + THR_);
    }
  if (__all(ok)) {
    // fast path: no cross-lane reduce, no rescale
#pragma unroll
    for (int qi = 0; qi < 2; qi++)
#pragma unroll
      for (int r = 0; r < 4; r++) {
        float m = mrun[qi][r];
        float lacc = lrun[qi][r];
#pragma unroll
        for (int ki = 0; ki < NK; ki++) {
          float p = __builtin_amdgcn_exp2f(s[qi][ki][r] - m);
          lacc += p;
          PlW[qi * (16 * PSTR) + (lgr * 4 + r) * PSTR + ki * 16 + lrow] = f2bf(p);
        }
        lrun[qi][r] = lacc;
      }
  } else {
#pragma unroll
    for (int qi = 0; qi < 2; qi++) {
      float corr[4];
#pragma unroll
      for (int r = 0; r < 4; r++) {
        float m0 = rm[qi][r];
#pragma unroll
        for (int off = 1; off < 16; off <<= 1) m0 = fmaxf(m0, __shfl_xor(m0, off));
        float mnew = fmaxf(mrun[qi][r], m0);
        float c = __builtin_amdgcn_exp2f(mrun[qi][r] - mnew);
        corr[r] = c;
        mrun[qi][r] = mnew;
        float lacc = lrun[qi][r] * c;
#pragma unroll
        for (int ki = 0; ki < NK; ki++) {
          float p = __builtin_amdgcn_exp2f(s[qi][ki][r] - mnew);
          lacc += p;
          PlW[qi * (16 * PSTR) + (lgr * 4 + r) * PSTR + ki * 16 + lrow] = f2bf(p);
        }
        lrun[qi][r] = lacc;
      }
#pragma unroll
      for (int nb = 0; nb < 4; nb++)
#pragma unroll
        for (int r = 0; r < 4; r++) o[qi][nb][r] *= corr[r];
    }
  }
#pragma unroll
  for (int sub = 0; sub < NK / 2; sub++) {
    bf16x8 pf0 = *(const bf16x8*)&PlW[0 * (16 * PSTR) + lrow * PSTR + sub * 32 + lgr * 8];
    bf16x8 pf1 = *(const bf16x8*)&PlW[1 * (16 * PSTR) + lrow * PSTR + sub * 32 + lgr * 8];
#pragma unroll
    for (int nb = 0; nb < 4; nb++) {
      bf16x8 vf = *(const bf16x8*)(Vh + (size_t)(nb * 16 + lrow) * S_ + kb + sub * 32 + lgr * 8);
      o[0][nb] = __builtin_amdgcn_mfma_f32_16x16x32_bf16(pf0, vf, o[0][nb], 0, 0, 0);
      o[1][nb] = __builtin_amdgcn_mfma_f32_16x16x32_bf16(pf1, vf, o[1][nb], 0, 0, 0);
    }
  }
}

__global__ __launch_bounds__(64) void attn_kernel(const u16* __restrict__ Q,
                                                  const u16* __restrict__ Kk,
                                                  const u16* __restrict__ Vt,
                                                  u16* __restrict__ ctx) {
  __shared__ __align__(16) u16 Pl[2][16 * PSTR];
  int t = threadIdx.x, lane = t & 63;
  // one wave per block; heavy strips dispatched first
  int strip = (S_ / 32) - 1 - (int)(blockIdx.x >> 6);
  int bh = blockIdx.x & 63;
  int b = bh >> 4, h = bh & 15;
  const u16* Qh = Q + (size_t)bh * S_ * HD_;
  const u16* Kh = Kk + (size_t)bh * S_ * HD_;
  const u16* Vh = Vt + (size_t)bh * HD_ * S_;
  u16* PlW = &Pl[0][0];
  int qbase = strip * 32;
  int lrow = lane & 15, lgr = lane >> 4;

  bf16x8 qf[2][2];
#pragma unroll
  for (int qi = 0; qi < 2; qi++)
#pragma unroll
    for (int kb = 0; kb < 2; kb++)
      qf[qi][kb] = *(const bf16x8*)(Qh + (size_t)(qbase + qi * 16 + lrow) * HD_ + kb * 32 + lgr * 8);

  f32x4 o[2][4] = {};
  float mrun[2][4], lrun[2][4];
#pragma unroll
  for (int qi = 0; qi < 2; qi++)
#pragma unroll
    for (int r = 0; r < 4; r++) { mrun[qi][r] = -1e30f; lrun[qi][r] = 0.f; }

  int nf64 = qbase >> 6;
  for (int kt = 0; kt < nf64; kt++)
    attn_chunk<4, false>(Kh, Vh, PlW, qf, o, mrun, lrun, kt * 64, qbase, lrow, lgr);
  if (qbase & 32)
    attn_chunk<2, false>(Kh, Vh, PlW, qf, o, mrun, lrun, qbase - 32, qbase, lrow, lgr);
  attn_chunk<2, true>(Kh, Vh, PlW, qf, o, mrun, lrun, qbase, qbase, lrow, lgr);

#pragma unroll
  for (int qi = 0; qi < 2; qi++) {
#pragma unroll
    for (int r = 0; r < 4; r++) {
      float l = lrun[qi][r];
#pragma unroll
      for (int off = 1; off < 16; off <<= 1) l += __shfl_xor(l, off);
      float inv = 1.0f / l;
      int srow = qbase + qi * 16 + lgr * 4 + r;
      size_t base = ((size_t)b * S_ + srow) * D_ + h * HD_;
#pragma unroll
      for (int nb = 0; nb < 4; nb++)
        ctx[base + nb * 16 + lrow] = f2bf(o[qi][nb][r] * inv);
    }
  }
}

extern "C" void kernel_launch(void* const* d_in, const int* in_sizes, int n_in,
                              void* d_out, int out_size, void* d_ws, size_t ws_size,
                              hipStream_t stream) {
  const float* x = (const float*)d_in[0];
  const float* ln1w = (const float*)d_in[1];
  const float* ln1b = (const float*)d_in[2];
  const float* wqkv = (const float*)d_in[3];
  const float* wproj = (const float*)d_in[4];
  const float* bproj = (const float*)d_in[5];
  const float* ln2w = (const float*)d_in[6];
  const float* ln2b = (const float*)d_in[7];
  const float* wff1 = (const float*)d_in[8];
  const float* bff1 = (const float*)d_in[9];
  const float* wff2 = (const float*)d_in[10];
  const float* bff2 = (const float*)d_in[11];

  char* ws = (char*)d_ws;
  u16* wqkvT = (u16*)(ws + 0);                 //  6 MB  [3072][1024]
  u16* wprojT = (u16*)(ws + 6291456);          //  2 MB  [1024][1024]
  u16* wff1T = (u16*)(ws + 8388608);           //  8 MB  [4096][1024]
  u16* wff2T = (u16*)(ws + 16777216);          //  8 MB  [1024][4096]
  u16* h1 = (u16*)(ws + 25165824);             // 16 MB  [8192][1024]; dead after QKV gemm
  u16* Vt = (u16*)(ws + 25165824);             // 16 MB  [bh][64][S]; written after h1 dead
  u16* Qc = (u16*)(ws + 41943040);             // 16 MB  [bh][S][64]
  u16* Kc = (u16*)(ws + 58720256);             // 16 MB
  u16* Vc = (u16*)(ws + 75497472);             // 16 MB  [bh][S][64]
  u16* ctx = (u16*)(ws + 92274688);            // 16 MB  [8192][1024]
  float* x1 = (float*)(ws + 109051904);        // 32 MB  [8192][1024]
  u16* h2 = (u16*)(ws + 142606336);            // 16 MB
  u16* g = (u16*)(ws + 25165824);              // 64 MB  [8192][4096]; overlays h1/Vt/Qc/Kc/Vc
  float* outp = (float*)d_out;

  wconv_kernel<<<(1024 / 32) * (3072 / 32), 256, 0, stream>>>(wqkv, wqkvT, 1024, 3072);
  wconv_kernel<<<(1024 / 32) * (1024 / 32), 256, 0, stream>>>(wproj, wprojT, 1024, 1024);
  wconv_kernel<<<(1024 / 32) * (4096 / 32), 256, 0, stream>>>(wff1, wff1T, 1024, 4096);
  wconv_kernel<<<(4096 / 32) * (1024 / 32), 256, 0, stream>>>(wff2, wff2T, 4096, 1024);

  ln_kernel<<<8192, 256, 0, stream>>>(x, ln1w, ln1b, h1);
  gemm_kernel<16><<<64 * 24, 256, 0, stream>>>(h1, wqkvT, nullptr, nullptr, nullptr, nullptr,
                                               Qc, Kc, Vc, 8192, 3072, 1024);
  vtrans_kernel<<<64 * 32, 256, 0, stream>>>(Vc, Vt);
  attn_kernel<<<64 * (S_ / 32), 64, 0, stream>>>(Qc, Kc, Vt, ctx);
  gemm_kernel<5><<<64 * 8, 256, 0, stream>>>(ctx, wprojT, bproj, x, x1, nullptr,
                                             nullptr, nullptr, nullptr, 8192, 1024, 1024);
  ln_kernel<<<8192, 256, 0, stream>>>(x1, ln2w, ln2b, h2);
  gemm_kernel<11><<<64 * 32, 256, 0, stream>>>(h2, wff1T, bff1, nullptr, nullptr, g,
                                               nullptr, nullptr, nullptr, 8192, 4096, 1024);
  gemm_kernel<5><<<64 * 8, 256, 0, stream>>>(g, wff2T, bff2, x1, outp, nullptr,
                                             nullptr, nullptr, nullptr, 8192, 1024, 4096);
}

// Round 4
// 484.105 us; speedup vs baseline: 1.3942x; 1.0892x over previous
//
#include <hip/hip_runtime.h>

typedef unsigned short u16;
typedef __bf16 bf16x8 __attribute__((ext_vector_type(8)));
typedef float f32x4 __attribute__((ext_vector_type(4)));
typedef unsigned short us8 __attribute__((ext_vector_type(8)));
typedef unsigned short us4 __attribute__((ext_vector_type(4)));

#define B_ 4
#define S_ 2048
#define D_ 1024
#define H_ 16
#define HD_ 64
#define EPS_ 1e-5f
#define PSTR 40  // P LDS row stride (elems)
#define SCALE_ (0.125f * 1.44269504088896341f)  // HD^-0.5 * log2(e); exp via exp2
#define THR_ 3.0f                               // defer-max threshold (log2 domain)

__device__ __forceinline__ u16 f2bf(float f) {
  unsigned u = __builtin_bit_cast(unsigned, f);
  u = (u + 0x7FFFu + ((u >> 16) & 1u)) >> 16;
  return (u16)u;
}

// tanh-form GELU via exp2: x*t/(1+t), t=exp2(2*c1*log2e*(x+c2*x^3)); |err| vs erf-GELU < 1e-3
__device__ __forceinline__ float gelu_f(float x) {
  float u = x * (2.3022388f + 0.10294971f * x * x);
  float te = __builtin_amdgcn_exp2f(u);
  return x - x * __builtin_amdgcn_rcpf(1.0f + te);
}

typedef const __attribute__((address_space(1))) unsigned int* gp1;
typedef __attribute__((address_space(3))) unsigned int* lp3;
__device__ __forceinline__ void gl_lds16(const void* g, void* l) {
  __builtin_amdgcn_global_load_lds((gp1)(unsigned long long)g,
                                   (lp3)(unsigned int)(unsigned long long)l,
                                   16, 0, 0);
}

// ---------------- weight transpose + f32->bf16 convert: W[K][N] -> Wt[N][K] ----------------
__global__ __launch_bounds__(256) void wconv_kernel(const float* __restrict__ W,
                                                    u16* __restrict__ Wt,
                                                    int Kd, int N) {
  __shared__ u16 tile[32][33];
  int bid = blockIdx.x;
  int nbn = N >> 5;
  int tk = bid / nbn, tn = bid % nbn;
  int tx = threadIdx.x & 31, ty = threadIdx.x >> 5;
#pragma unroll
  for (int i = 0; i < 4; i++) {
    int r = ty + i * 8;
    tile[r][tx] = f2bf(W[(size_t)(tk * 32 + r) * N + tn * 32 + tx]);
  }
  __syncthreads();
#pragma unroll
  for (int i = 0; i < 4; i++) {
    int r = ty + i * 8;
    Wt[(size_t)(tn * 32 + r) * Kd + tk * 32 + tx] = tile[tx][r];
  }
}

// ---------------- V transpose: Vc [bh][S][64] -> Vt [bh][64][S] ----------------------------
__global__ __launch_bounds__(256) void vtrans_kernel(const u16* __restrict__ Vc,
                                                     u16* __restrict__ Vt) {
  __shared__ u16 tile[64][72];
  int bh = blockIdx.x >> 5;
  int sb = blockIdx.x & 31;
  const u16* src = Vc + ((size_t)bh * S_ + sb * 64) * HD_;
  int r = threadIdx.x >> 2, c0 = (threadIdx.x & 3) * 16;
  *(us8*)&tile[r][c0] = *(const us8*)(src + r * HD_ + c0);
  *(us8*)&tile[r][c0 + 8] = *(const us8*)(src + r * HD_ + c0 + 8);
  __syncthreads();
  u16* dst = Vt + (size_t)bh * HD_ * S_ + sb * 64;
  int hd = threadIdx.x >> 2;
  int s0 = (threadIdx.x & 3) * 16;
  us8 a, b;
#pragma unroll
  for (int j = 0; j < 8; j++) a[j] = tile[s0 + j][hd];
#pragma unroll
  for (int j = 0; j < 8; j++) b[j] = tile[s0 + 8 + j][hd];
  *(us8*)(dst + (size_t)hd * S_ + s0) = a;
  *(us8*)(dst + (size_t)hd * S_ + s0 + 8) = b;
}

// ---------------- LayerNorm: f32 in -> bf16 out, one block per row (D=1024) ----------------
__global__ __launch_bounds__(256) void ln_kernel(const float* __restrict__ x,
                                                 const float* __restrict__ w,
                                                 const float* __restrict__ b,
                                                 u16* __restrict__ out) {
  int row = blockIdx.x;
  int t = threadIdx.x;
  int lane = t & 63, wid = t >> 6;
  const float4* xr = (const float4*)(x + (size_t)row * D_);
  float4 v = xr[t];
  float s = v.x + v.y + v.z + v.w;
  float q = v.x * v.x + v.y * v.y + v.z * v.z + v.w * v.w;
#pragma unroll
  for (int off = 1; off < 64; off <<= 1) {
    s += __shfl_xor(s, off);
    q += __shfl_xor(q, off);
  }
  __shared__ float red[8];
  if (lane == 0) { red[wid] = s; red[4 + wid] = q; }
  __syncthreads();
  s = red[0] + red[1] + red[2] + red[3];
  q = red[4] + red[5] + red[6] + red[7];
  float mu = s * (1.0f / D_);
  float var = q * (1.0f / D_) - mu * mu;
  float rs = rsqrtf(var + EPS_);
  int c = t * 4;
  float4 wv = *(const float4*)(w + c);
  float4 bv = *(const float4*)(b + c);
  us4 o;
  o[0] = f2bf((v.x - mu) * rs * wv.x + bv.x);
  o[1] = f2bf((v.y - mu) * rs * wv.y + bv.y);
  o[2] = f2bf((v.z - mu) * rs * wv.z + bv.z);
  o[3] = f2bf((v.w - mu) * rs * wv.w + bv.w);
  *(us4*)(out + (size_t)row * D_ + c) = o;
}

// ---------------- GEMM: BK=64, T2 XOR-swizzled LDS (pre-swizzled global src, linear dest) --
// MODE bits: 1=bias, 2=gelu, 4=residual(f32), 8=bf16 out, 16=QKV interleaved split store
template <int MODE>
__global__ __launch_bounds__(256) void gemm_kernel(
    const u16* __restrict__ A, const u16* __restrict__ Bt,
    const float* __restrict__ bias, const float* __restrict__ res,
    float* __restrict__ Cf, u16* __restrict__ Cb,
    u16* __restrict__ Qc, u16* __restrict__ Kc, u16* __restrict__ Vc,
    int M, int N, int K) {
  __shared__ __align__(16) u16 Al[128 * 64];
  __shared__ __align__(16) u16 Bl[128 * 64];
  int t = threadIdx.x;
  int nbn = N >> 7;
  int nwg = gridDim.x;
  int cpx = nwg >> 3;
  int bid = (blockIdx.x % 8) * cpx + blockIdx.x / 8;
  int bm = bid / nbn, bn = bid % nbn;
  int lane = t & 63, wid = t >> 6;
  int wm = wid >> 1, wn = wid & 1;
  int lrow = lane & 15, lgr = lane >> 4;
  const u16* Ab = A + (size_t)bm * 128 * K;
  const u16* Bb = Bt + (size_t)bn * 128 * K;
  // staging: instr j (0..3), wave w: rows [(j*4+w)*8, +8). lane l -> row +=(l>>3),
  // swizzled source col slot ((l&7)^(l>>3)); LDS dest stays linear (gl_lds requirement).
  int sr = lane >> 3;
  int sc = ((lane & 7) ^ sr) << 3;  // elems
  const u16* Ag[4];
  const u16* Bg[4];
  u16* Ald[4];
  u16* Bld[4];
#pragma unroll
  for (int j = 0; j < 4; j++) {
    int row0 = (j * 4 + wid) * 8;
    Ag[j] = Ab + (size_t)(row0 + sr) * K + sc;
    Bg[j] = Bb + (size_t)(row0 + sr) * K + sc;
    Ald[j] = &Al[row0 * 64 + lane * 8];
    Bld[j] = &Bl[row0 * 64 + lane * 8];
  }
  int sl7 = lrow & 7;  // row&7 for all fragment rows this lane reads
  f32x4 acc[4][4] = {};
  for (int k0 = 0; k0 < K; k0 += 64) {
#pragma unroll
    for (int j = 0; j < 4; j++) {
      gl_lds16(Ag[j] + k0, Ald[j]);
      gl_lds16(Bg[j] + k0, Bld[j]);
    }
    __syncthreads();  // drains vmcnt(0): tile resident
    bf16x8 af[2][4], bfr[2][4];
#pragma unroll
    for (int ks = 0; ks < 2; ks++) {
      int slot = ((ks << 2) | lgr) ^ sl7;  // 16B slot after swizzle
#pragma unroll
      for (int m = 0; m < 4; m++)
        af[ks][m] = *(const bf16x8*)&Al[(wm * 64 + m * 16 + lrow) * 64 + slot * 8];
#pragma unroll
      for (int n = 0; n < 4; n++)
        bfr[ks][n] = *(const bf16x8*)&Bl[(wn * 64 + n * 16 + lrow) * 64 + slot * 8];
    }
#pragma unroll
    for (int m = 0; m < 4; m++)
#pragma unroll
      for (int n = 0; n < 4; n++) {
        acc[m][n] = __builtin_amdgcn_mfma_f32_16x16x32_bf16(af[0][m], bfr[0][n], acc[m][n], 0, 0, 0);
        acc[m][n] = __builtin_amdgcn_mfma_f32_16x16x32_bf16(af[1][m], bfr[1][n], acc[m][n], 0, 0, 0);
      }
    __syncthreads();  // all waves done reading before next overwrite
  }
  // epilogue: n outer so col-derived address math is hoisted
#pragma unroll
  for (int n = 0; n < 4; n++) {
    int col = bn * 128 + wn * 64 + n * 16 + lrow;
    float bv = (MODE & 1) ? bias[col] : 0.0f;
    if (MODE & 16) {
      // col factors as (h, hd, c) with c fastest; c=0:K, c=1:Q, c=2:V (all [bh][S][64])
      int c = col % 3;
      int hd = (col / 3) & 63;
      int h = col / 192;
      u16* dst = (c == 0) ? Kc : (c == 1) ? Qc : Vc;
#pragma unroll
      for (int m = 0; m < 4; m++)
#pragma unroll
        for (int r = 0; r < 4; r++) {
          int row = bm * 128 + wm * 64 + m * 16 + lgr * 4 + r;
          int bb = row >> 11, sIdx = row & 2047;
          dst[(((size_t)(bb * H_ + h)) * S_ + sIdx) * HD_ + hd] = f2bf(acc[m][n][r]);
        }
    } else {
#pragma unroll
      for (int m = 0; m < 4; m++)
#pragma unroll
        for (int r = 0; r < 4; r++) {
          int row = bm * 128 + wm * 64 + m * 16 + lgr * 4 + r;
          float v = acc[m][n][r] + bv;
          if (MODE & 2) v = gelu_f(v);
          if (MODE & 4) v += res[(size_t)row * N + col];
          if (MODE & 8) Cb[(size_t)row * N + col] = f2bf(v);
          else          Cf[(size_t)row * N + col] = v;
        }
    }
  }
}

// ---------------- causal flash attention -------------------------------------------------
// Q,K [bh][S][64] bf16, Vt [bh][64][S] bf16. One wave per 32 q rows.
// Defer-max (THR, log2 domain) + per-lane deferred l-sum (reduced once at end).
template <int NK, bool MASK>
__device__ __forceinline__ void attn_chunk(
    const u16* __restrict__ Kh, const u16* __restrict__ Vh, u16* PlW,
    const bf16x8 (&qf)[2][2], f32x4 (&o)[2][4],
    float (&mrun)[2][4], float (&lrun)[2][4],
    int kb, int qbase, int lrow, int lgr) {
  bf16x8 kf[NK][2];
#pragma unroll
  for (int ki = 0; ki < NK; ki++)
#pragma unroll
    for (int h = 0; h < 2; h++)
      kf[ki][h] = *(const bf16x8*)(Kh + (size_t)(kb + ki * 16 + lrow) * HD_ + h * 32 + lgr * 8);
  f32x4 s[2][NK];
#pragma unroll
  for (int qi = 0; qi < 2; qi++)
#pragma unroll
    for (int ki = 0; ki < NK; ki++) {
      f32x4 z = {0.f, 0.f, 0.f, 0.f};
      z = __builtin_amdgcn_mfma_f32_16x16x32_bf16(qf[qi][0], kf[ki][0], z, 0, 0, 0);
      z = __builtin_amdgcn_mfma_f32_16x16x32_bf16(qf[qi][1], kf[ki][1], z, 0, 0, 0);
      s[qi][ki] = z;
    }
  float rm[2][4];
  bool ok = true;
#pragma unroll
  for (int qi = 0; qi < 2; qi++)
#pragma unroll
    for (int r = 0; r < 4; r++) {
      float m0 = -3.0e38f;
#pragma unroll
      for (int ki = 0; ki < NK; ki++) {
        float v = s[qi][ki][r] * SCALE_;
        if (MASK) {
          int qrow = qbase + qi * 16 + lgr * 4 + r;
          int kcol = kb + ki * 16 + lrow;
          if (kcol > qrow) v = -3.0e38f;
        }
        s[qi][ki][r] = v;
        m0 = fmaxf(m0, v);
      }
      rm[qi][r] = m0;
      ok = ok && (m0 <= mrun[qi][r] + THR_);
    }
  if (__all(ok)) {
#pragma unroll
    for (int qi = 0; qi < 2; qi++)
#pragma unroll
      for (int r = 0; r < 4; r++) {
        float m = mrun[qi][r];
        float lacc = lrun[qi][r];
#pragma unroll
        for (int ki = 0; ki < NK; ki++) {
          float p = __builtin_amdgcn_exp2f(s[qi][ki][r] - m);
          lacc += p;
          PlW[qi * (16 * PSTR) + (lgr * 4 + r) * PSTR + ki * 16 + lrow] = f2bf(p);
        }
        lrun[qi][r] = lacc;
      }
  } else {
#pragma unroll
    for (int qi = 0; qi < 2; qi++) {
      float corr[4];
#pragma unroll
      for (int r = 0; r < 4; r++) {
        float m0 = rm[qi][r];
#pragma unroll
        for (int off = 1; off < 16; off <<= 1) m0 = fmaxf(m0, __shfl_xor(m0, off));
        float mnew = fmaxf(mrun[qi][r], m0);
        float c = __builtin_amdgcn_exp2f(mrun[qi][r] - mnew);
        corr[r] = c;
        mrun[qi][r] = mnew;
        float lacc = lrun[qi][r] * c;
#pragma unroll
        for (int ki = 0; ki < NK; ki++) {
          float p = __builtin_amdgcn_exp2f(s[qi][ki][r] - mnew);
          lacc += p;
          PlW[qi * (16 * PSTR) + (lgr * 4 + r) * PSTR + ki * 16 + lrow] = f2bf(p);
        }
        lrun[qi][r] = lacc;
      }
#pragma unroll
      for (int nb = 0; nb < 4; nb++)
#pragma unroll
        for (int r = 0; r < 4; r++) o[qi][nb][r] *= corr[r];
    }
  }
#pragma unroll
  for (int sub = 0; sub < NK / 2; sub++) {
    bf16x8 pf0 = *(const bf16x8*)&PlW[0 * (16 * PSTR) + lrow * PSTR + sub * 32 + lgr * 8];
    bf16x8 pf1 = *(const bf16x8*)&PlW[1 * (16 * PSTR) + lrow * PSTR + sub * 32 + lgr * 8];
#pragma unroll
    for (int nb = 0; nb < 4; nb++) {
      bf16x8 vf = *(const bf16x8*)(Vh + (size_t)(nb * 16 + lrow) * S_ + kb + sub * 32 + lgr * 8);
      o[0][nb] = __builtin_amdgcn_mfma_f32_16x16x32_bf16(pf0, vf, o[0][nb], 0, 0, 0);
      o[1][nb] = __builtin_amdgcn_mfma_f32_16x16x32_bf16(pf1, vf, o[1][nb], 0, 0, 0);
    }
  }
}

__global__ __launch_bounds__(64) void attn_kernel(const u16* __restrict__ Q,
                                                  const u16* __restrict__ Kk,
                                                  const u16* __restrict__ Vt,
                                                  u16* __restrict__ ctx) {
  __shared__ __align__(16) u16 Pl[2][16 * PSTR];
  int t = threadIdx.x, lane = t & 63;
  int strip = (S_ / 32) - 1 - (int)(blockIdx.x >> 6);
  int bh = blockIdx.x & 63;
  int b = bh >> 4, h = bh & 15;
  const u16* Qh = Q + (size_t)bh * S_ * HD_;
  const u16* Kh = Kk + (size_t)bh * S_ * HD_;
  const u16* Vh = Vt + (size_t)bh * HD_ * S_;
  u16* PlW = &Pl[0][0];
  int qbase = strip * 32;
  int lrow = lane & 15, lgr = lane >> 4;

  bf16x8 qf[2][2];
#pragma unroll
  for (int qi = 0; qi < 2; qi++)
#pragma unroll
    for (int kb = 0; kb < 2; kb++)
      qf[qi][kb] = *(const bf16x8*)(Qh + (size_t)(qbase + qi * 16 + lrow) * HD_ + kb * 32 + lgr * 8);

  f32x4 o[2][4] = {};
  float mrun[2][4], lrun[2][4];
#pragma unroll
  for (int qi = 0; qi < 2; qi++)
#pragma unroll
    for (int r = 0; r < 4; r++) { mrun[qi][r] = -1e30f; lrun[qi][r] = 0.f; }

  int nf64 = qbase >> 6;
  for (int kt = 0; kt < nf64; kt++)
    attn_chunk<4, false>(Kh, Vh, PlW, qf, o, mrun, lrun, kt * 64, qbase, lrow, lgr);
  if (qbase & 32)
    attn_chunk<2, false>(Kh, Vh, PlW, qf, o, mrun, lrun, qbase - 32, qbase, lrow, lgr);
  attn_chunk<2, true>(Kh, Vh, PlW, qf, o, mrun, lrun, qbase, qbase, lrow, lgr);

#pragma unroll
  for (int qi = 0; qi < 2; qi++) {
#pragma unroll
    for (int r = 0; r < 4; r++) {
      float l = lrun[qi][r];
#pragma unroll
      for (int off = 1; off < 16; off <<= 1) l += __shfl_xor(l, off);
      float inv = 1.0f / l;
      int srow = qbase + qi * 16 + lgr * 4 + r;
      size_t base = ((size_t)b * S_ + srow) * D_ + h * HD_;
#pragma unroll
      for (int nb = 0; nb < 4; nb++)
        ctx[base + nb * 16 + lrow] = f2bf(o[qi][nb][r] * inv);
    }
  }
}

extern "C" void kernel_launch(void* const* d_in, const int* in_sizes, int n_in,
                              void* d_out, int out_size, void* d_ws, size_t ws_size,
                              hipStream_t stream) {
  const float* x = (const float*)d_in[0];
  const float* ln1w = (const float*)d_in[1];
  const float* ln1b = (const float*)d_in[2];
  const float* wqkv = (const float*)d_in[3];
  const float* wproj = (const float*)d_in[4];
  const float* bproj = (const float*)d_in[5];
  const float* ln2w = (const float*)d_in[6];
  const float* ln2b = (const float*)d_in[7];
  const float* wff1 = (const float*)d_in[8];
  const float* bff1 = (const float*)d_in[9];
  const float* wff2 = (const float*)d_in[10];
  const float* bff2 = (const float*)d_in[11];

  char* ws = (char*)d_ws;
  u16* wqkvT = (u16*)(ws + 0);                 //  6 MB  [3072][1024]
  u16* wprojT = (u16*)(ws + 6291456);          //  2 MB  [1024][1024]
  u16* wff1T = (u16*)(ws + 8388608);           //  8 MB  [4096][1024]
  u16* wff2T = (u16*)(ws + 16777216);          //  8 MB  [1024][4096]
  u16* h1 = (u16*)(ws + 25165824);             // 16 MB  [8192][1024]; dead after QKV gemm
  u16* Vt = (u16*)(ws + 25165824);             // 16 MB  [bh][64][S]; written after h1 dead
  u16* Qc = (u16*)(ws + 41943040);             // 16 MB  [bh][S][64]
  u16* Kc = (u16*)(ws + 58720256);             // 16 MB
  u16* Vc = (u16*)(ws + 75497472);             // 16 MB  [bh][S][64]
  u16* ctx = (u16*)(ws + 92274688);            // 16 MB  [8192][1024]
  float* x1 = (float*)(ws + 109051904);        // 32 MB  [8192][1024]
  u16* h2 = (u16*)(ws + 142606336);            // 16 MB
  u16* g = (u16*)(ws + 25165824);              // 64 MB  [8192][4096]; overlays h1/Vt/Qc/Kc/Vc
  float* outp = (float*)d_out;

  wconv_kernel<<<(1024 / 32) * (3072 / 32), 256, 0, stream>>>(wqkv, wqkvT, 1024, 3072);
  wconv_kernel<<<(1024 / 32) * (1024 / 32), 256, 0, stream>>>(wproj, wprojT, 1024, 1024);
  wconv_kernel<<<(1024 / 32) * (4096 / 32), 256, 0, stream>>>(wff1, wff1T, 1024, 4096);
  wconv_kernel<<<(4096 / 32) * (1024 / 32), 256, 0, stream>>>(wff2, wff2T, 4096, 1024);

  ln_kernel<<<8192, 256, 0, stream>>>(x, ln1w, ln1b, h1);
  gemm_kernel<16><<<64 * 24, 256, 0, stream>>>(h1, wqkvT, nullptr, nullptr, nullptr, nullptr,
                                               Qc, Kc, Vc, 8192, 3072, 1024);
  vtrans_kernel<<<64 * 32, 256, 0, stream>>>(Vc, Vt);
  attn_kernel<<<64 * (S_ / 32), 64, 0, stream>>>(Qc, Kc, Vt, ctx);
  gemm_kernel<5><<<64 * 8, 256, 0, stream>>>(ctx, wprojT, bproj, x, x1, nullptr,
                                             nullptr, nullptr, nullptr, 8192, 1024, 1024);
  ln_kernel<<<8192, 256, 0, stream>>>(x1, ln2w, ln2b, h2);
  gemm_kernel<11><<<64 * 32, 256, 0, stream>>>(h2, wff1T, bff1, nullptr, nullptr, g,
                                               nullptr, nullptr, nullptr, 8192, 4096, 1024);
  gemm_kernel<5><<<64 * 8, 256, 0, stream>>>(g, wff2T, bff2, x1, outp, nullptr,
                                             nullptr, nullptr, nullptr, 8192, 1024, 4096);
}